// Round 1
// baseline (577.795 us; speedup 1.0000x reference)
//
#include <hip/hip_runtime.h>
#include <hip/hip_bf16.h>
#include <stdint.h>

#define B_SZ 32
#define S_SZ 4096
#define H_SZ 512
#define U_SZ 512
// M = B*S = 131072 rows, K = H = 512, N = U = 512

typedef __attribute__((ext_vector_type(8)))  _Float16 half8;
typedef __attribute__((ext_vector_type(4)))  _Float16 half4_t;
typedef __attribute__((ext_vector_type(16))) float    floatx16;

// ---------------------------------------------------------------------------
// Kernel 0a: qpb2[b][u] = query[b]·W1[:,u] + b1[u] + b2[u]   (fp32 exact)
// ---------------------------------------------------------------------------
__global__ __launch_bounds__(256) void qproj_kernel(
    const float* __restrict__ query, const float* __restrict__ W1,
    const float* __restrict__ b1, const float* __restrict__ b2,
    float* __restrict__ qpb2)
{
    const int b = blockIdx.x;          // 0..31
    const int u = blockIdx.y * 256 + threadIdx.x;  // 0..511
    float acc = b1[u] + b2[u];
    const float* q = query + b * H_SZ;
    for (int h = 0; h < H_SZ; ++h)
        acc += q[h] * W1[h * U_SZ + u];
    qpb2[b * U_SZ + u] = acc;
}

// ---------------------------------------------------------------------------
// Kernel 0b: W2 (fp32 [K][N]) -> W2s (f16, frag-major [kb][khalf][n][8])
//   k = kb*16 + khalf*8 + kk  ->  idx = kb*8192 + khalf*4096 + n*8 + kk
// ---------------------------------------------------------------------------
__global__ __launch_bounds__(256) void w2swizzle_kernel(
    const float* __restrict__ W2, _Float16* __restrict__ W2s)
{
    const int i = blockIdx.x * 256 + threadIdx.x;   // 0..262143
    const int k = i >> 9;
    const int n = i & 511;
    const int idx = (k >> 4) * 8192 + ((k >> 3) & 1) * 4096 + n * 8 + (k & 7);
    W2s[idx] = (_Float16)W2[i];
}

// ---------------------------------------------------------------------------
// Kernel 1: fused scores.  Block = 64 M-rows x full N=512, 4 waves.
// Wave w: all 64 rows x n-range [w*128, w*128+128) = 4 tiles of 32x32.
// K-loop: 32 steps of BK=16 using mfma_f32_32x32x16_f16.
// Epilogue: score[m] = bva + sum_n tanh(vproj + qpb2[b][n]) * va[n]
// ---------------------------------------------------------------------------
__global__ __launch_bounds__(256, 2) void scores_kernel(
    const float* __restrict__ values, const _Float16* __restrict__ W2s,
    const float* __restrict__ qpb2, const float* __restrict__ va,
    const float* __restrict__ bva, float* __restrict__ scores)
{
    // A_lds: [khalf][64 m][8]  (f16)   = 1024 halfs = 2 KB
    // B_lds: [khalf][512 n][8] (f16)   = 8192 halfs = 16 KB
    __shared__ __align__(16) _Float16 A_lds[1024];
    __shared__ __align__(16) _Float16 B_lds[8192];
    __shared__ float sc[64 * 33];                       // padded reduce matrix

    const int t    = threadIdx.x;
    const int lane = t & 63;
    const int w    = t >> 6;
    const int l31  = lane & 31;
    const int kh   = lane >> 5;        // khalf for frags
    const int m0   = blockIdx.x * 64;
    const int b    = m0 >> 12;         // m0 / 4096

    const float* Arow = values + (size_t)m0 * H_SZ;

    floatx16 acc[2][4];
#pragma unroll
    for (int s = 0; s < 2; ++s)
#pragma unroll
        for (int nt = 0; nt < 4; ++nt) acc[s][nt] = (floatx16)(0.0f);

    // A staging assignment: thread t -> row sm = t>>2, float4 chunk kq = t&3
    const int sm = t >> 2;
    const int kq = t & 3;
    const int aw = ((kq >> 1) * 64 + sm) * 8 + (kq & 1) * 4;  // half index

    const uint4* Wsrc = reinterpret_cast<const uint4*>(W2s);  // 8 halfs / uint4
    uint4* Bl4 = reinterpret_cast<uint4*>(B_lds);

    for (int kb = 0; kb < 32; ++kb) {
        __syncthreads();
        // stage A: 64 x 16 fp32 -> f16
        float4 av = *reinterpret_cast<const float4*>(Arow + sm * H_SZ + kb * 16 + kq * 4);
        half4_t ah;
        ah.x = (_Float16)av.x; ah.y = (_Float16)av.y;
        ah.z = (_Float16)av.z; ah.w = (_Float16)av.w;
        *reinterpret_cast<half4_t*>(&A_lds[aw]) = ah;
        // stage B: contiguous 16 KB copy (coalesced from L2)
#pragma unroll
        for (int i = 0; i < 4; ++i)
            Bl4[t * 4 + i] = Wsrc[kb * 1024 + t * 4 + i];
        __syncthreads();

        // frags (lane-consecutive 16B reads -> conflict-free ds_read_b128)
        half8 a0 = *reinterpret_cast<const half8*>(&A_lds[kh * 512 + l31 * 8]);
        half8 a1 = *reinterpret_cast<const half8*>(&A_lds[kh * 512 + 256 + l31 * 8]);
#pragma unroll
        for (int nt = 0; nt < 4; ++nt) {
            half8 bf = *reinterpret_cast<const half8*>(
                &B_lds[kh * 4096 + ((w * 4 + nt) * 32 + l31) * 8]);
            acc[0][nt] = __builtin_amdgcn_mfma_f32_32x32x16_f16(a0, bf, acc[0][nt], 0, 0, 0);
            acc[1][nt] = __builtin_amdgcn_mfma_f32_32x32x16_f16(a1, bf, acc[1][nt], 0, 0, 0);
        }
    }

    // ---- epilogue: tanh + va-dot + cross-lane reduce ----
    float qv[4], vv[4];
#pragma unroll
    for (int nt = 0; nt < 4; ++nt) {
        int n = w * 128 + nt * 32 + l31;
        qv[nt] = qpb2[b * U_SZ + n];
        vv[nt] = va[n];
    }
    __syncthreads();
    for (int i = t; i < 64 * 33; i += 256) sc[i] = 0.0f;
    __syncthreads();
#pragma unroll
    for (int s = 0; s < 2; ++s) {
#pragma unroll
        for (int r = 0; r < 16; ++r) {
            float p = 0.0f;
#pragma unroll
            for (int nt = 0; nt < 4; ++nt) {
                float x = acc[s][nt][r] + qv[nt];
                float e = __expf(2.0f * x);
                p += (1.0f - 2.0f / (e + 1.0f)) * vv[nt];   // tanh(x)
            }
            int ml = s * 32 + (r & 3) + 8 * (r >> 2) + 4 * kh;
            atomicAdd(&sc[ml * 33 + l31], p);
        }
    }
    __syncthreads();
    if (t < 64) {
        float sum = *bva;
#pragma unroll
        for (int c = 0; c < 32; ++c) sum += sc[t * 33 + c];
        scores[m0 + t] = sum;
    }
}

// ---------------------------------------------------------------------------
// Kernel 2: softmax over S per batch; writes attention_weights to d_out and
// zeroes the context region (for kernel 3's atomics).
// ---------------------------------------------------------------------------
__global__ __launch_bounds__(1024) void softmax_kernel(
    const float* __restrict__ scores, float* __restrict__ out)
{
    __shared__ float red[16];
    __shared__ float s_max, s_sum;
    const int b = blockIdx.x;
    const int t = threadIdx.x;  // 0..1023

    float4 v = *reinterpret_cast<const float4*>(scores + b * S_SZ + t * 4);
    float m = fmaxf(fmaxf(v.x, v.y), fmaxf(v.z, v.w));
#pragma unroll
    for (int o = 32; o > 0; o >>= 1) m = fmaxf(m, __shfl_xor(m, o));
    if ((t & 63) == 0) red[t >> 6] = m;
    __syncthreads();
    if (t == 0) {
        float mm = red[0];
        for (int i = 1; i < 16; ++i) mm = fmaxf(mm, red[i]);
        s_max = mm;
    }
    __syncthreads();
    float mm = s_max;
    float4 e;
    e.x = __expf(v.x - mm); e.y = __expf(v.y - mm);
    e.z = __expf(v.z - mm); e.w = __expf(v.w - mm);
    float s = e.x + e.y + e.z + e.w;
#pragma unroll
    for (int o = 32; o > 0; o >>= 1) s += __shfl_xor(s, o);
    if ((t & 63) == 0) red[t >> 6] = s;
    __syncthreads();
    if (t == 0) {
        float ss = 0.0f;
        for (int i = 0; i < 16; ++i) ss += red[i];
        s_sum = ss;
    }
    __syncthreads();
    float rinv = 1.0f / s_sum;
    float4 wv;
    wv.x = e.x * rinv; wv.y = e.y * rinv; wv.z = e.z * rinv; wv.w = e.w * rinv;
    *reinterpret_cast<float4*>(out + b * S_SZ + t * 4) = wv;

    if (t < 512) out[B_SZ * S_SZ + b * 512 + t] = 0.0f;  // zero context region
}

// ---------------------------------------------------------------------------
// Kernel 3: context[b][h] = sum_s w[b][s] * values[b][s][h]
// grid (ssplit=8, hc=2, b=32); block 256 = 4 s-groups x 64 lanes (float4 h)
// ---------------------------------------------------------------------------
__global__ __launch_bounds__(256) void context_kernel(
    const float* __restrict__ values, const float* __restrict__ wts,
    float* __restrict__ ctx)
{
    __shared__ float wl[512];
    __shared__ __align__(16) float part[4][64][4];
    const int ss = blockIdx.x;   // 0..7
    const int hc = blockIdx.y;   // 0..1
    const int b  = blockIdx.z;   // 0..31
    const int t  = threadIdx.x;
    const int l = t & 63, g = t >> 6;

    if (t < 128)
        *reinterpret_cast<float4*>(&wl[t * 4]) =
            *reinterpret_cast<const float4*>(wts + b * S_SZ + ss * 512 + t * 4);
    __syncthreads();

    const int h = hc * 256 + l * 4;
    const float* vp = values + ((size_t)(b * S_SZ + ss * 512 + g * 128)) * H_SZ + h;
    float4 a = {0.f, 0.f, 0.f, 0.f};
    for (int i = 0; i < 128; ++i) {
        float wv = wl[g * 128 + i];
        float4 v = *reinterpret_cast<const float4*>(vp + (size_t)i * H_SZ);
        a.x += wv * v.x; a.y += wv * v.y; a.z += wv * v.z; a.w += wv * v.w;
    }
    *reinterpret_cast<float4*>(&part[g][l][0]) = a;
    __syncthreads();
    if (t < 64) {
        float4 sacc = *reinterpret_cast<float4*>(&part[0][t][0]);
#pragma unroll
        for (int gg = 1; gg < 4; ++gg) {
            float4 p = *reinterpret_cast<float4*>(&part[gg][t][0]);
            sacc.x += p.x; sacc.y += p.y; sacc.z += p.z; sacc.w += p.w;
        }
        int hh = hc * 256 + t * 4;
        atomicAdd(&ctx[b * H_SZ + hh + 0], sacc.x);
        atomicAdd(&ctx[b * H_SZ + hh + 1], sacc.y);
        atomicAdd(&ctx[b * H_SZ + hh + 2], sacc.z);
        atomicAdd(&ctx[b * H_SZ + hh + 3], sacc.w);
    }
}

// ---------------------------------------------------------------------------
extern "C" void kernel_launch(void* const* d_in, const int* in_sizes, int n_in,
                              void* d_out, int out_size, void* d_ws, size_t ws_size,
                              hipStream_t stream) {
    const float* query  = (const float*)d_in[0];   // [32,512]
    const float* values = (const float*)d_in[1];   // [32,4096,512]
    const float* W1     = (const float*)d_in[2];   // [512,512]
    const float* b1     = (const float*)d_in[3];   // [512]
    const float* W2     = (const float*)d_in[4];   // [512,512]
    const float* b2     = (const float*)d_in[5];   // [512]
    const float* va     = (const float*)d_in[6];   // [512,1]
    const float* bva    = (const float*)d_in[7];   // [1]
    float* out = (float*)d_out;  // [32*4096 weights][32*512 context]

    // workspace layout
    char* ws = (char*)d_ws;
    float*    qpb2   = (float*)ws;                       // 64 KB
    _Float16* W2s    = (_Float16*)(ws + 65536);          // 512 KB
    float*    scores = (float*)(ws + 65536 + 524288);    // 512 KB

    qproj_kernel<<<dim3(32, 2), 256, 0, stream>>>(query, W1, b1, b2, qpb2);
    w2swizzle_kernel<<<1024, 256, 0, stream>>>(W2, W2s);
    scores_kernel<<<2048, 256, 0, stream>>>(values, W2s, qpb2, va, bva, scores);
    softmax_kernel<<<32, 1024, 0, stream>>>(scores, out);
    context_kernel<<<dim3(8, 2, 32), 256, 0, stream>>>(values, out, out + B_SZ * S_SZ);
}

// Round 2
// 545.925 us; speedup vs baseline: 1.0584x; 1.0584x over previous
//
#include <hip/hip_runtime.h>
#include <hip/hip_bf16.h>
#include <stdint.h>

#define B_SZ 32
#define S_SZ 4096
#define H_SZ 512
#define U_SZ 512

typedef __attribute__((ext_vector_type(8))) _Float16 half8;
typedef __attribute__((ext_vector_type(4))) float floatx4;

__device__ __forceinline__ void async_copy16(const void* g, void* l) {
    __builtin_amdgcn_global_load_lds(
        (const __attribute__((address_space(1))) void*)g,
        (__attribute__((address_space(3))) void*)l, 16, 0, 0);
}

// ---------------------------------------------------------------------------
// prep: W2 fp32 [k][n] -> W2s f16 kq-major [kb][kq][n][8]  (k = kb*32+kq*8+kk)
//       + zero qpb2 and ctx (for later atomics)
// ---------------------------------------------------------------------------
__global__ __launch_bounds__(256) void prep_kernel(
    const float* __restrict__ W2, _Float16* __restrict__ W2s,
    float* __restrict__ qpb2, float* __restrict__ ctx)
{
    const int t = threadIdx.x;
    const int bid = blockIdx.x;
    const int i = bid * 256 + t;          // 0..262143
    const int k = i >> 9, n = i & 511;
    W2s[(k >> 5) * 16384 + ((k >> 3) & 3) * 4096 + n * 8 + (k & 7)] =
        (_Float16)W2[i];
    if (bid < 64) qpb2[i] = 0.0f;                       // 16384 floats
    else if (bid < 128) ctx[(bid - 64) * 256 + t] = 0.0f;  // 16384 floats
}

// ---------------------------------------------------------------------------
// qproj: qpb2[b][u] += partial(query[b]·W1[:,u]) + (b1+b2 on ks==0), k-split 4
// ---------------------------------------------------------------------------
__global__ __launch_bounds__(256) void qproj_kernel(
    const float* __restrict__ query, const float* __restrict__ W1,
    const float* __restrict__ b1, const float* __restrict__ b2,
    float* __restrict__ qpb2)
{
    const int b = blockIdx.x, uc = blockIdx.y, ks = blockIdx.z;
    const int u = uc * 256 + threadIdx.x;
    float acc = (ks == 0) ? (b1[u] + b2[u]) : 0.0f;
    const float* q  = query + b * H_SZ + ks * 128;
    const float* Wp = W1 + (size_t)(ks * 128) * U_SZ + u;
    for (int k = 0; k < 128; ++k)
        acc = fmaf(q[k], Wp[(size_t)k * U_SZ], acc);
    atomicAdd(&qpb2[b * U_SZ + u], acc);
}

// ---------------------------------------------------------------------------
// scores: per block 64 m-rows x full N=512.  BK=32, 16 K-steps, 1 barrier/step.
// B: dbuf LDS via global_load_lds(16B).  A: registers only (prefetch + cvt).
// mfma_f32_16x16x32_f16: wave w owns n-range [w*128, w*128+128) (8 subtiles)
// x 64 m (4 subtiles) = 32 MFMA per K-step per wave.
// Epilogue: score[m] = bva + sum_n tanh(vproj+qpb2)·va  (shuffle reduce).
// ---------------------------------------------------------------------------
__global__ __launch_bounds__(256, 2) void scores_kernel(
    const float* __restrict__ values, const _Float16* __restrict__ W2s,
    const float* __restrict__ qpb2, const float* __restrict__ va,
    const float* __restrict__ bva, float* __restrict__ scores)
{
    __shared__ __align__(16) char smem[65536];   // B dbuf 2x32KB; epilogue reuse

    const int t  = threadIdx.x;
    const int w  = t >> 6;        // wave 0..3
    const int l  = t & 63;
    const int c  = l & 15;        // frag row/col within 16
    const int g4 = l >> 4;        // k-quad 0..3
    const int m0 = blockIdx.x * 64;
    const int b  = m0 >> 12;

    const float* Abase = values + (size_t)m0 * H_SZ;

    floatx4 acc[4][8];
#pragma unroll
    for (int mt = 0; mt < 4; ++mt)
#pragma unroll
        for (int nt = 0; nt < 8; ++nt) acc[mt][nt] = (floatx4)(0.0f);

    // prologue: B slab 0 -> buf0 (async), A kb=0 -> regs
    {
        const char* src = (const char*)W2s;
#pragma unroll
        for (int i = 0; i < 8; ++i)
            async_copy16(src + (i * 256 + t) * 16, smem + (i * 256 + t) * 16);
    }
    float4 Apre[4][2];
    {
        const int ko = g4 * 8;
#pragma unroll
        for (int mt = 0; mt < 4; ++mt) {
            const float* ap = Abase + (size_t)(mt * 16 + c) * H_SZ + ko;
            Apre[mt][0] = *(const float4*)(ap);
            Apre[mt][1] = *(const float4*)(ap + 4);
        }
    }
    __syncthreads();   // drains vmcnt: buf0 ready

    for (int kb = 0; kb < 16; ++kb) {
        const int cur = kb & 1;
        // convert current A to f16 frags
        half8 af[4];
#pragma unroll
        for (int mt = 0; mt < 4; ++mt) {
            half8 a;
            a[0] = (_Float16)Apre[mt][0].x; a[1] = (_Float16)Apre[mt][0].y;
            a[2] = (_Float16)Apre[mt][0].z; a[3] = (_Float16)Apre[mt][0].w;
            a[4] = (_Float16)Apre[mt][1].x; a[5] = (_Float16)Apre[mt][1].y;
            a[6] = (_Float16)Apre[mt][1].z; a[7] = (_Float16)Apre[mt][1].w;
            af[mt] = a;
        }
        if (kb < 15) {
            // prefetch next A (consumed next iteration)
            const int ko = (kb + 1) * 32 + g4 * 8;
#pragma unroll
            for (int mt = 0; mt < 4; ++mt) {
                const float* ap = Abase + (size_t)(mt * 16 + c) * H_SZ + ko;
                Apre[mt][0] = *(const float4*)(ap);
                Apre[mt][1] = *(const float4*)(ap + 4);
            }
            // async-stage next B slab into the other buffer
            const char* src = (const char*)W2s + (size_t)(kb + 1) * 32768;
            char* dst = smem + (cur ^ 1) * 32768;
#pragma unroll
            for (int i = 0; i < 8; ++i)
                async_copy16(src + (i * 256 + t) * 16, dst + (i * 256 + t) * 16);
        }
        // B frags: lane-consecutive 16B ds_reads (conflict-free)
        const _Float16* Bc = (const _Float16*)(smem + cur * 32768);
        half8 bf[8];
#pragma unroll
        for (int nt = 0; nt < 8; ++nt)
            bf[nt] = *(const half8*)(Bc + g4 * 4096 + (w * 128 + nt * 16 + c) * 8);
#pragma unroll
        for (int mt = 0; mt < 4; ++mt)
#pragma unroll
            for (int nt = 0; nt < 8; ++nt)
                acc[mt][nt] = __builtin_amdgcn_mfma_f32_16x16x32_f16(
                    af[mt], bf[nt], acc[mt][nt], 0, 0, 0);
        __syncthreads();   // all reads of buf[cur] done; next-B DMA drained
    }

    // ---- epilogue ----
    float qv2[8], vv[8], vv2[8];
#pragma unroll
    for (int nt = 0; nt < 8; ++nt) {
        const int n = w * 128 + nt * 16 + c;
        const float q = qpb2[b * U_SZ + n];
        const float v = va[n];
        qv2[nt] = 2.0f * q;
        vv[nt] = v;
        vv2[nt] = 2.0f * v;
    }
    float* red = (float*)smem;   // 64 rows x 4 waves (overlays buf0; safe)
#pragma unroll
    for (int mt = 0; mt < 4; ++mt) {
#pragma unroll
        for (int r = 0; r < 4; ++r) {
            float p = 0.0f;
#pragma unroll
            for (int nt = 0; nt < 8; ++nt) {
                const float ex = __expf(fmaf(acc[mt][nt][r], 2.0f, qv2[nt]));
                const float rc = __builtin_amdgcn_rcpf(ex + 1.0f);
                p = fmaf(-vv2[nt], rc, p + vv[nt]);   // += tanh(x)*va
            }
            p += __shfl_xor(p, 1);
            p += __shfl_xor(p, 2);
            p += __shfl_xor(p, 4);
            p += __shfl_xor(p, 8);
            if (c == 0) red[(mt * 16 + g4 * 4 + r) * 4 + w] = p;
        }
    }
    __syncthreads();
    if (t < 64)
        scores[m0 + t] = *bva + red[t * 4 + 0] + red[t * 4 + 1] +
                         red[t * 4 + 2] + red[t * 4 + 3];
}

// ---------------------------------------------------------------------------
// sredux: per-batch softmax stats (max M, denom L) only
// ---------------------------------------------------------------------------
__global__ __launch_bounds__(1024) void sredux_kernel(
    const float* __restrict__ scores, float* __restrict__ ML)
{
    __shared__ float red[16];
    __shared__ float s_max;
    const int b = blockIdx.x;
    const int t = threadIdx.x;
    float4 v = *(const float4*)(scores + b * S_SZ + t * 4);
    float m = fmaxf(fmaxf(v.x, v.y), fmaxf(v.z, v.w));
#pragma unroll
    for (int o = 32; o > 0; o >>= 1) m = fmaxf(m, __shfl_xor(m, o));
    if ((t & 63) == 0) red[t >> 6] = m;
    __syncthreads();
    if (t == 0) {
        float mm = red[0];
        for (int i = 1; i < 16; ++i) mm = fmaxf(mm, red[i]);
        s_max = mm;
    }
    __syncthreads();
    const float mm = s_max;
    float s = __expf(v.x - mm) + __expf(v.y - mm) +
              __expf(v.z - mm) + __expf(v.w - mm);
#pragma unroll
    for (int o = 32; o > 0; o >>= 1) s += __shfl_xor(s, o);
    if ((t & 63) == 0) red[t >> 6] = s;
    __syncthreads();
    if (t == 0) {
        float ss = 0.0f;
        for (int i = 0; i < 16; ++i) ss += red[i];
        ML[b * 2] = mm;
        ML[b * 2 + 1] = ss;
    }
}

// ---------------------------------------------------------------------------
// context: computes weights on the fly (exp(sc-M)/L), writes them (hc==0),
// and accumulates context[b][h] = sum_s w*values.  grid (16 ss, 2 hc, 32 b).
// ---------------------------------------------------------------------------
__global__ __launch_bounds__(256) void context_kernel(
    const float* __restrict__ values, const float* __restrict__ scores,
    const float* __restrict__ ML, float* __restrict__ out)
{
    __shared__ float wl[256];
    __shared__ __align__(16) float part[4][64][4];
    const int ss = blockIdx.x, hc = blockIdx.y, b = blockIdx.z;
    const int t = threadIdx.x;
    const float M = ML[b * 2];
    const float rL = 1.0f / ML[b * 2 + 1];
    const int s = ss * 256 + t;
    const float wv = __expf(scores[b * S_SZ + s] - M) * rL;
    wl[t] = wv;
    if (hc == 0) out[b * S_SZ + s] = wv;   // attention_weights output
    __syncthreads();

    const int l = t & 63, g = t >> 6;
    const int h = hc * 256 + l * 4;
    const float* vp = values + ((size_t)b * S_SZ + ss * 256 + g * 64) * H_SZ + h;
    float4 a0 = {0.f, 0.f, 0.f, 0.f}, a1 = {0.f, 0.f, 0.f, 0.f};
    for (int i = 0; i < 64; i += 2) {
        const float w0 = wl[g * 64 + i];
        const float w1 = wl[g * 64 + i + 1];
        float4 v0 = *(const float4*)(vp + (size_t)i * H_SZ);
        float4 v1 = *(const float4*)(vp + (size_t)(i + 1) * H_SZ);
        a0.x = fmaf(w0, v0.x, a0.x); a0.y = fmaf(w0, v0.y, a0.y);
        a0.z = fmaf(w0, v0.z, a0.z); a0.w = fmaf(w0, v0.w, a0.w);
        a1.x = fmaf(w1, v1.x, a1.x); a1.y = fmaf(w1, v1.y, a1.y);
        a1.z = fmaf(w1, v1.z, a1.z); a1.w = fmaf(w1, v1.w, a1.w);
    }
    a0.x += a1.x; a0.y += a1.y; a0.z += a1.z; a0.w += a1.w;
    *(float4*)&part[g][l][0] = a0;
    __syncthreads();
    if (t < 64) {
        float4 sa = *(float4*)&part[0][t][0];
#pragma unroll
        for (int gg = 1; gg < 4; ++gg) {
            float4 p = *(float4*)&part[gg][t][0];
            sa.x += p.x; sa.y += p.y; sa.z += p.z; sa.w += p.w;
        }
        float* ctx = out + B_SZ * S_SZ;
        const int hh = hc * 256 + t * 4;
        atomicAdd(&ctx[b * H_SZ + hh + 0], sa.x);
        atomicAdd(&ctx[b * H_SZ + hh + 1], sa.y);
        atomicAdd(&ctx[b * H_SZ + hh + 2], sa.z);
        atomicAdd(&ctx[b * H_SZ + hh + 3], sa.w);
    }
}

// ---------------------------------------------------------------------------
extern "C" void kernel_launch(void* const* d_in, const int* in_sizes, int n_in,
                              void* d_out, int out_size, void* d_ws, size_t ws_size,
                              hipStream_t stream) {
    const float* query  = (const float*)d_in[0];
    const float* values = (const float*)d_in[1];
    const float* W1     = (const float*)d_in[2];
    const float* b1     = (const float*)d_in[3];
    const float* W2     = (const float*)d_in[4];
    const float* b2     = (const float*)d_in[5];
    const float* va     = (const float*)d_in[6];
    const float* bva    = (const float*)d_in[7];
    float* out = (float*)d_out;   // [32*4096 weights][32*512 context]

    char* ws = (char*)d_ws;
    float*    qpb2   = (float*)ws;                                  // 64 KB
    _Float16* W2s    = (_Float16*)(ws + 65536);                     // 512 KB
    float*    scores = (float*)(ws + 65536 + 524288);               // 512 KB
    float*    ML     = (float*)(ws + 65536 + 524288 + 524288);      // 256 B

    float* ctx = out + B_SZ * S_SZ;

    prep_kernel<<<1024, 256, 0, stream>>>(W2, W2s, qpb2, ctx);
    qproj_kernel<<<dim3(32, 2, 4), 256, 0, stream>>>(query, W1, b1, b2, qpb2);
    scores_kernel<<<2048, 256, 0, stream>>>(values, W2s, qpb2, va, bva, scores);
    sredux_kernel<<<32, 1024, 0, stream>>>(scores, ML);
    context_kernel<<<dim3(16, 2, 32), 256, 0, stream>>>(values, scores, ML, out);
}